// Round 6
// baseline (296.932 us; speedup 1.0000x reference)
//
#include <hip/hip_runtime.h>

#define Bv 32
#define Sv 128
#define Tv 2000
#define Dv 768
#define Hv 256
#define Rv 50
#define CHF 16            // frames per chunk
#define NCH 125           // chunks per batch (125*16 = 2000)

// ---------------------------------------------------------------------------
// stage1: blocks [0,4000): 16-frame chunk sums (audio streamed exactly once)
//         blocks [4000,4256): wpad (mlp1_w K padded 250->256)
//         blocks [4256,4768): word/pos gathers into x0 (8 tokens/block)
//         blocks [4768,4818): rwc[r,:] = rw[r,:256] @ aw  (arc-head fold)
//         block  4818:        rbc[r] = rw[r,:256] @ ab + rb[r]
// ---------------------------------------------------------------------------
__global__ __launch_bounds__(256) void stage1(
    const float* __restrict__ audio, const int* __restrict__ words,
    const int* __restrict__ pos_ids, const float* __restrict__ word_W,
    const float* __restrict__ pos_W, const float* __restrict__ m1w,
    const float* __restrict__ rw, const float* __restrict__ aw,
    const float* __restrict__ ab, const float* __restrict__ rb,
    float* __restrict__ chunkSum, float* __restrict__ wpad,
    float* __restrict__ x0, float* __restrict__ rwc, float* __restrict__ rbc)
{
  const int tid = threadIdx.x;
  const int blk = blockIdx.x;

  if (blk < Bv * NCH) {
    const int b = blk / NCH;
    const int c = blk - b * NCH;
    const float* base = audio + ((size_t)b * Tv + c * CHF) * Dv;
    float s0 = 0.f, s1 = 0.f, s2 = 0.f;
#pragma unroll
    for (int f = 0; f < CHF; ++f) {
      const float* row = base + (size_t)f * Dv;
      s0 += row[tid];
      s1 += row[tid + 256];
      s2 += row[tid + 512];
    }
    float* o = chunkSum + (size_t)blk * Dv;
    o[tid] = s0; o[tid + 256] = s1; o[tid + 512] = s2;
  } else if (blk < Bv * NCH + 256) {
    const int idx = (blk - Bv * NCH) * 256 + tid;
    const int r = idx >> 8, cc = idx & 255;
    wpad[idx] = (cc < 250) ? m1w[r * 250 + cc] : 0.0f;
  } else if (blk < Bv * NCH + 256 + 512) {
    const int base = (blk - Bv * NCH - 256) * 8;
#pragma unroll
    for (int rep = 0; rep < 8; ++rep) {
      const int tok = base + rep;
      if (tid < 100) {
        x0[(size_t)tok * 256 + tid] = word_W[(size_t)words[tok] * 100 + tid];
      } else if (tid < 150) {
        x0[(size_t)tok * 256 + tid] = pos_W[pos_ids[tok] * 50 + (tid - 100)];
      } else if (tid >= 250) {
        x0[(size_t)tok * 256 + tid] = 0.0f;
      }
    }
  } else if (blk < Bv * NCH + 256 + 512 + Rv) {
    // rwc[r, tid] = sum_h rw[r*512 + h] * aw[h*256 + tid]
    const int r = blk - (Bv * NCH + 256 + 512);
    const float* rwr = rw + (size_t)r * 512;
    float acc = 0.f;
#pragma unroll 4
    for (int h = 0; h < 256; ++h)
      acc += rwr[h] * aw[(size_t)h * 256 + tid];
    rwc[(size_t)r * 256 + tid] = acc;
  } else {
    // rbc[r] = rb[r] + sum_h rw[r*512+h]*ab[h]
    if (tid < Rv) {
      const float* rwr = rw + (size_t)tid * 512;
      float acc = rb[tid];
      for (int h = 0; h < 256; ++h) acc += rwr[h] * ab[h];
      rbc[tid] = acc;
    }
  }
}

// ---------------------------------------------------------------------------
// seg_proj: per token, seg mean = (full chunk sums + head/tail partial frames)
// * 1/cnt, then fused 768->100 projection into x0[:,150:250].
// grid = 4096 tokens, block = 256.
// ---------------------------------------------------------------------------
__global__ __launch_bounds__(256) void seg_proj(
    const float* __restrict__ audio, const float* __restrict__ chunkSum,
    const float* __restrict__ st, const float* __restrict__ et,
    const float* __restrict__ audio_w, const float* __restrict__ audio_b,
    float* __restrict__ x0)
{
  const int tok = blockIdx.x;
  const int b = tok >> 7;
  const int tid = threadIdx.x;

  __shared__ float sm[768];
  __shared__ float shalf[200];

  const float stime = st[tok], etime = et[tok];
  const int si = (int)(stime * 50.0f);   // trunc == floor for >= 0
  const int ei = (int)(etime * 50.0f);
  const bool valid = (ei > si) && (ei <= Tv);
  const int sc = min(max(si, 0), Tv);
  const int ec = min(max(ei, 0), Tv);
  const float m = valid ? (1.0f / (float)max(ec - sc, 1)) : 0.0f;

  const int cA = (sc + CHF - 1) >> 4;    // first full chunk
  const int cB = ec >> 4;                // one past last full chunk

  float a0 = 0.f, a1 = 0.f, a2 = 0.f;
  const float* abase = audio + (size_t)b * Tv * Dv;

  if (cA <= cB) {
    const float* csb = chunkSum + (size_t)b * NCH * Dv;
    for (int c = cA; c < cB; ++c) {          // <= 5 iterations
      const float* r = csb + (size_t)c * Dv;
      a0 += r[tid]; a1 += r[tid + 256]; a2 += r[tid + 512];
    }
    for (int f = sc; f < cA * CHF; ++f) {    // head partial, <= 15
      const float* r = abase + (size_t)f * Dv;
      a0 += r[tid]; a1 += r[tid + 256]; a2 += r[tid + 512];
    }
    for (int f = cB * CHF; f < ec; ++f) {    // tail partial, <= 15
      const float* r = abase + (size_t)f * Dv;
      a0 += r[tid]; a1 += r[tid + 256]; a2 += r[tid + 512];
    }
  } else {
    for (int f = sc; f < ec; ++f) {          // segment inside one chunk
      const float* r = abase + (size_t)f * Dv;
      a0 += r[tid]; a1 += r[tid + 256]; a2 += r[tid + 512];
    }
  }

  sm[tid] = a0 * m; sm[tid + 256] = a1 * m; sm[tid + 512] = a2 * m;
  __syncthreads();

  // projection: threads 0..199, half-dot each (k in [h*384, h*384+384))
  if (tid < 200) {
    const int h = (tid >= 100);
    const int p = tid - h * 100;
    const float4* wr = (const float4*)(audio_w + (size_t)p * Dv + h * 384);
    const float4* mr = (const float4*)(sm + h * 384);
    float acc = 0.f;
#pragma unroll 4
    for (int k = 0; k < 96; ++k) {
      const float4 v = wr[k], u = mr[k];
      acc += v.x * u.x + v.y * u.y + v.z * u.z + v.w * u.w;
    }
    shalf[tid] = acc;
  }
  __syncthreads();

  if (tid < 100)
    x0[(size_t)tok * 256 + 150 + tid] = shalf[tid] + shalf[tid + 100]
                                        + audio_b[tid];
}

// ---------------------------------------------------------------------------
// GEMM core: 32x64 tile, 256 threads, 2x4 acc/thread, reg-prefetch K-chunks.
// ---------------------------------------------------------------------------
template<bool BIAS, bool RELU>
__device__ __forceinline__ void gemm_core(
    const float* __restrict__ A, int lda,
    const float* __restrict__ W, int ldw,
    const float* __restrict__ bias,
    float* __restrict__ C, int ldc, int c0,
    int N, int K, int row0, int n0)
{
  __shared__ float sA[16][34];
  __shared__ float sB[16][68];

  const int tid = threadIdx.x;
  const int tm = tid >> 4;
  const int tn = tid & 15;

  float acc[2][4] = {};

  const int rowA = tid >> 2;
  const int kq = (tid & 3) << 2;
  const bool aact = tid < 128;
  const bool wval = (n0 + rowA) < N;

  const float* Ap = A + (size_t)(row0 + (rowA & 31)) * lda + kq;
  const float* Wp = W + (size_t)(wval ? (n0 + rowA) : 0) * ldw + kq;

  float4 av = float4{0, 0, 0, 0}, bv = float4{0, 0, 0, 0};
  if (aact) av = *(const float4*)Ap;
  if (wval) bv = *(const float4*)Wp;

  int k0 = 0;
  while (true) {
    __syncthreads();
    if (aact) {
      sA[kq + 0][rowA] = av.x; sA[kq + 1][rowA] = av.y;
      sA[kq + 2][rowA] = av.z; sA[kq + 3][rowA] = av.w;
    }
    sB[kq + 0][rowA] = bv.x; sB[kq + 1][rowA] = bv.y;
    sB[kq + 2][rowA] = bv.z; sB[kq + 3][rowA] = bv.w;
    __syncthreads();

    const int kn = k0 + 16;
    const bool more = kn < K;
    if (more) {
      if (aact) av = *(const float4*)(Ap + kn);
      if (wval) bv = *(const float4*)(Wp + kn);
    }

#pragma unroll
    for (int kk = 0; kk < 16; ++kk) {
      const float2 a = *(const float2*)&sA[kk][tm * 2];
      const float4 b = *(const float4*)&sB[kk][tn * 4];
      acc[0][0] += a.x * b.x; acc[0][1] += a.x * b.y;
      acc[0][2] += a.x * b.z; acc[0][3] += a.x * b.w;
      acc[1][0] += a.y * b.x; acc[1][1] += a.y * b.y;
      acc[1][2] += a.y * b.z; acc[1][3] += a.y * b.w;
    }

    if (!more) break;
    k0 = kn;
  }

#pragma unroll
  for (int i = 0; i < 2; ++i) {
    const int row = row0 + tm * 2 + i;
    float* crow = C + (size_t)row * ldc + c0;
#pragma unroll
    for (int j = 0; j < 4; ++j) {
      const int col = n0 + tn * 4 + j;
      if (col < N) {
        float v = acc[i][j];
        if (BIAS) v += bias[col];
        if (RELU) v = fmaxf(v, 0.0f);
        crow[col] = v;
      }
    }
  }
}

template<bool BIAS, bool RELU>
__global__ __launch_bounds__(256) void gemm_tn(
    const float* __restrict__ A, int lda,
    const float* __restrict__ W, int ldw,
    const float* __restrict__ bias,
    float* __restrict__ C, int ldc, int c0,
    int N, int K)
{
  gemm_core<BIAS, RELU>(A, lda, W, ldw, bias, C, ldc, c0, N, K,
                        blockIdx.x * 32, blockIdx.y * 64);
}

// ---------------------------------------------------------------------------
// heads: everything downstream of xfeat in one launch.
//  y in [0,4): head = xfeat @ aw^T + ab      (64-col slabs)
//  y == 4:    relh = xfeat @ rwc^T + rbc    (arc-head folded into rel_h)
//  y == 5:    reld = xfeat @ rw[:,256:]^T
// ---------------------------------------------------------------------------
__global__ __launch_bounds__(256) void heads(
    const float* __restrict__ xfeat, const float* __restrict__ aw,
    const float* __restrict__ ab, const float* __restrict__ rwc,
    const float* __restrict__ rbc, const float* __restrict__ rw,
    float* __restrict__ head, float* __restrict__ relh,
    float* __restrict__ reld)
{
  const int y = blockIdx.y;
  if (y < 4)
    gemm_core<true, false>(xfeat, 256, aw, 256, ab, head, 256, 0,
                           256, 256, blockIdx.x * 32, y * 64);
  else if (y == 4)
    gemm_core<true, false>(xfeat, 256, rwc, 256, rbc, relh, 50, 0,
                           50, 256, blockIdx.x * 32, 0);
  else
    gemm_core<false, false>(xfeat, 256, rw + 256, 512, nullptr, reld, 50, 0,
                            50, 256, blockIdx.x * 32, 0);
}

// ---------------------------------------------------------------------------
// Fused scores: blocks [0,512) arc 32x32 tiles; [512,4608) rel broadcast-add.
// ---------------------------------------------------------------------------
__global__ __launch_bounds__(256) void fused_scores(
    const float* __restrict__ head, const float* __restrict__ dep,
    const float* __restrict__ relh, const float* __restrict__ reld,
    float* __restrict__ arc_out, float* __restrict__ rel_out)
{
  __shared__ float smem[6450];
  const int tid = threadIdx.x;

  if (blockIdx.x < 512) {
    const int blk = blockIdx.x;
    const int b = blk >> 4;
    const int tile = blk & 15;
    const int i0 = (tile >> 2) * 32;
    const int j0 = (tile & 3) * 32;

    float (*sh)[33] = (float(*)[33])smem;
    float (*sd)[33] = (float(*)[33])(smem + 1056);

    const int r = tid >> 3;
    const int c = (tid & 7) << 2;
    const int ty = tid >> 4;
    const int tx = tid & 15;

    float acc00 = 0.f, acc01 = 0.f, acc10 = 0.f, acc11 = 0.f;
    const float* hb = head + (size_t)(b * Sv + i0) * Hv;
    const float* db = dep + (size_t)(b * Sv + j0) * Hv;

    for (int k0 = 0; k0 < Hv; k0 += 32) {
      float4 hv = *(const float4*)(hb + (size_t)r * Hv + k0 + c);
      float4 dv = *(const float4*)(db + (size_t)r * Hv + k0 + c);
      __syncthreads();
      sh[r][c] = hv.x; sh[r][c+1] = hv.y; sh[r][c+2] = hv.z; sh[r][c+3] = hv.w;
      sd[r][c] = dv.x; sd[r][c+1] = dv.y; sd[r][c+2] = dv.z; sd[r][c+3] = dv.w;
      __syncthreads();
#pragma unroll
      for (int kk = 0; kk < 32; ++kk) {
        float h0 = sh[ty][kk],  h1 = sh[ty + 16][kk];
        float d0 = sd[tx][kk],  d1 = sd[tx + 16][kk];
        acc00 += h0 * d0; acc01 += h0 * d1;
        acc10 += h1 * d0; acc11 += h1 * d1;
      }
    }

    float* ob = arc_out + (size_t)b * Sv * Sv;
    ob[(i0 + ty) * Sv + j0 + tx]           = acc00;
    ob[(i0 + ty) * Sv + j0 + tx + 16]      = acc01;
    ob[(i0 + ty + 16) * Sv + j0 + tx]      = acc10;
    ob[(i0 + ty + 16) * Sv + j0 + tx + 16] = acc11;
  } else {
    const int bi = blockIdx.x - 512;
    const int b = bi >> 7;

    float* srd = smem;
    float* shi = smem + 6400;

    const float4* rd4 = (const float4*)(reld + (size_t)b * Sv * Rv);
    float4* s4 = (float4*)srd;
    for (int n = tid; n < (Sv * Rv / 4); n += 256) s4[n] = rd4[n];
    if (tid < Rv) shi[tid] = relh[(size_t)bi * Rv + tid];
    __syncthreads();

    float2* out2 = (float2*)(rel_out + (size_t)bi * Sv * Rv);
    for (int n = tid; n < (Sv * Rv / 2); n += 256) {
      const int j = n / 25;
      const int r = (n - j * 25) * 2;
      const float* rdj = srd + j * Rv;
      float2 v;
      v.x = shi[r]     + rdj[r];
      v.y = shi[r + 1] + rdj[r + 1];
      out2[n] = v;
    }
  }
}

// ---------------------------------------------------------------------------
extern "C" void kernel_launch(void* const* d_in, const int* in_sizes, int n_in,
                              void* d_out, int out_size, void* d_ws, size_t ws_size,
                              hipStream_t stream) {
  const int*   words   = (const int*)d_in[0];
  const int*   pos_ids = (const int*)d_in[1];
  const float* audio   = (const float*)d_in[2];
  const float* st      = (const float*)d_in[3];
  const float* et      = (const float*)d_in[4];
  const float* word_W  = (const float*)d_in[5];
  const float* pos_W   = (const float*)d_in[6];
  const float* audio_w = (const float*)d_in[7];
  const float* audio_b = (const float*)d_in[8];
  const float* m1w     = (const float*)d_in[9];
  const float* m1b     = (const float*)d_in[10];
  const float* m2w     = (const float*)d_in[11];
  const float* m2b     = (const float*)d_in[12];
  const float* aw      = (const float*)d_in[13];
  const float* ab      = (const float*)d_in[14];
  const float* rw      = (const float*)d_in[15];
  const float* rb      = (const float*)d_in[16];

  float* out = (float*)d_out;
  float* ws = (float*)d_ws;

  const size_t NT = (size_t)Bv * Sv;            // 4096 tokens
  float* chunkSum = ws;                         // 32*125*768 = 3.072M floats
  float* x0    = chunkSum + (size_t)Bv * NCH * Dv;  // NT*256
  float* h1    = x0    + NT * 256;              // NT*256
  float* xfeat = h1    + NT * 256;              // NT*256 (dep)
  float* head  = xfeat + NT * 256;              // NT*256
  float* relh  = head  + NT * 256;              // NT*50
  float* reld  = relh  + NT * Rv;               // NT*50
  float* wpad  = reld  + NT * Rv;               // 256*256
  float* rwc   = wpad  + 256 * 256;             // 50*256
  float* rbc   = rwc   + Rv * 256;              // 50

  stage1<<<Bv * NCH + 256 + 512 + Rv + 1, 256, 0, stream>>>(
      audio, words, pos_ids, word_W, pos_W, m1w, rw, aw, ab, rb,
      chunkSum, wpad, x0, rwc, rbc);

  seg_proj<<<(int)NT, 256, 0, stream>>>(
      audio, chunkSum, st, et, audio_w, audio_b, x0);

  // mlp1: h1 = relu(x0 @ wpad.T + m1b)
  gemm_tn<true, true><<<dim3(128, 4), 256, 0, stream>>>(
      x0, 256, wpad, 256, m1b, h1, 256, 0, 256, 256);

  // mlp2: xfeat = relu(h1 @ m2w.T + m2b)
  gemm_tn<true, true><<<dim3(128, 4), 256, 0, stream>>>(
      h1, 256, m2w, 256, m2b, xfeat, 256, 0, 256, 256);

  // head / relh / reld in one launch
  heads<<<dim3(128, 6), 256, 0, stream>>>(
      xfeat, aw, ab, rwc, rbc, rw, head, relh, reld);

  fused_scores<<<512 + (int)NT, 256, 0, stream>>>(
      head, xfeat, relh, reld, out, out + (size_t)Bv * Sv * Sv);
}

// Round 7
// 185.888 us; speedup vs baseline: 1.5974x; 1.5974x over previous
//
#include <hip/hip_runtime.h>

#define Bv 32
#define Sv 128
#define Tv 2000
#define Dv 768
#define Hv 256
#define Rv 50
#define CHF 8             // frames per chunk
#define NCH 250           // chunks per batch (250*8 = 2000)

// ---------------------------------------------------------------------------
// stage1: blocks [0,8000): 8-frame chunk sums (audio streamed exactly once)
//         blocks [8000,8256): wpad (mlp1_w K padded 250->256)
//         blocks [8256,8768): word/pos gathers into x0 (8 tokens/block)
//         blocks [8768,8818): rwc[r,:] = rw[r,:256] @ aw  (arc-head fold)
//         block  8818:        rbc[r] = rw[r,:256] @ ab + rb[r]
// ---------------------------------------------------------------------------
__global__ __launch_bounds__(256) void stage1(
    const float* __restrict__ audio, const int* __restrict__ words,
    const int* __restrict__ pos_ids, const float* __restrict__ word_W,
    const float* __restrict__ pos_W, const float* __restrict__ m1w,
    const float* __restrict__ rw, const float* __restrict__ aw,
    const float* __restrict__ ab, const float* __restrict__ rb,
    float* __restrict__ chunkSum, float* __restrict__ wpad,
    float* __restrict__ x0, float* __restrict__ rwc, float* __restrict__ rbc)
{
  const int tid = threadIdx.x;
  const int blk = blockIdx.x;

  if (blk < Bv * NCH) {
    const int b = blk / NCH;
    const int c = blk - b * NCH;
    const float* base = audio + ((size_t)b * Tv + c * CHF) * Dv;
    float s0 = 0.f, s1 = 0.f, s2 = 0.f;
#pragma unroll
    for (int f = 0; f < CHF; ++f) {
      const float* row = base + (size_t)f * Dv;
      s0 += row[tid];
      s1 += row[tid + 256];
      s2 += row[tid + 512];
    }
    float* o = chunkSum + (size_t)blk * Dv;
    o[tid] = s0; o[tid + 256] = s1; o[tid + 512] = s2;
  } else if (blk < Bv * NCH + 256) {
    const int idx = (blk - Bv * NCH) * 256 + tid;
    const int r = idx >> 8, cc = idx & 255;
    wpad[idx] = (cc < 250) ? m1w[r * 250 + cc] : 0.0f;
  } else if (blk < Bv * NCH + 256 + 512) {
    const int base = (blk - Bv * NCH - 256) * 8;
#pragma unroll
    for (int rep = 0; rep < 8; ++rep) {
      const int tok = base + rep;
      if (tid < 100) {
        x0[(size_t)tok * 256 + tid] = word_W[(size_t)words[tok] * 100 + tid];
      } else if (tid < 150) {
        x0[(size_t)tok * 256 + tid] = pos_W[pos_ids[tok] * 50 + (tid - 100)];
      } else if (tid >= 250) {
        x0[(size_t)tok * 256 + tid] = 0.0f;
      }
    }
  } else if (blk < Bv * NCH + 256 + 512 + Rv) {
    // rwc[r, k] = sum_h rw[r,h] * aw[h,k]
    const int r = blk - (Bv * NCH + 256 + 512);
    const float* rwr = rw + (size_t)r * 512;
    float acc = 0.f;
#pragma unroll 4
    for (int h = 0; h < 256; ++h)
      acc += rwr[h] * aw[(size_t)h * 256 + tid];
    rwc[(size_t)r * 256 + tid] = acc;
  } else {
    // rbc[r] = rb[r] + sum_h rw[r,h]*ab[h]
    if (tid < Rv) {
      const float* rwr = rw + (size_t)tid * 512;
      float acc = rb[tid];
      for (int h = 0; h < 256; ++h) acc += rwr[h] * ab[h];
      rbc[tid] = acc;
    }
  }
}

// ---------------------------------------------------------------------------
// seg_sum: per token, segment mean via pointer list (full chunks from
// chunkSum + head/tail partial frames from audio), all additions.
// grid = 4096 tokens, block = 256 (3 dims/thread), unroll-4 over list.
// ---------------------------------------------------------------------------
__global__ __launch_bounds__(256) void seg_sum(
    const float* __restrict__ audio, const float* __restrict__ chunkSum,
    const float* __restrict__ st, const float* __restrict__ et,
    float* __restrict__ smean)
{
  const int tok = blockIdx.x;
  const int b = tok >> 7;
  const int tid = threadIdx.x;

  __shared__ const float* plist[40];
  __shared__ int pn;

  const float stime = st[tok], etime = et[tok];
  const int si = (int)(stime * 50.0f);   // trunc == floor for >= 0
  const int ei = (int)(etime * 50.0f);
  const bool valid = (ei > si) && (ei <= Tv);
  const int sc = min(max(si, 0), Tv);
  const int ec = min(max(ei, 0), Tv);
  const float m = valid ? (1.0f / (float)max(ec - sc, 1)) : 0.0f;

  if (tid == 0) {
    const float* abase = audio + (size_t)b * Tv * Dv;
    const float* csb = chunkSum + (size_t)b * NCH * Dv;
    const int cA = (sc + CHF - 1) / CHF;   // first full chunk
    const int cB = ec / CHF;               // one past last full chunk
    int n = 0;
    if (cA <= cB) {
      for (int f = sc; f < cA * CHF; ++f) plist[n++] = abase + (size_t)f * Dv;
      for (int c = cA; c < cB; ++c)       plist[n++] = csb + (size_t)c * Dv;
      for (int f = cB * CHF; f < ec; ++f) plist[n++] = abase + (size_t)f * Dv;
    } else {
      for (int f = sc; f < ec; ++f)       plist[n++] = abase + (size_t)f * Dv;
    }
    pn = n;
  }
  __syncthreads();

  float a0 = 0.f, a1 = 0.f, a2 = 0.f;
  const int n = pn;
  int i = 0;
  for (; i + 4 <= n; i += 4) {
    const float* p0 = plist[i];
    const float* p1 = plist[i + 1];
    const float* p2 = plist[i + 2];
    const float* p3 = plist[i + 3];
    a0 += p0[tid]       + p1[tid]       + p2[tid]       + p3[tid];
    a1 += p0[tid + 256] + p1[tid + 256] + p2[tid + 256] + p3[tid + 256];
    a2 += p0[tid + 512] + p1[tid + 512] + p2[tid + 512] + p3[tid + 512];
  }
  for (; i < n; ++i) {
    const float* p = plist[i];
    a0 += p[tid]; a1 += p[tid + 256]; a2 += p[tid + 512];
  }

  float* o = smean + (size_t)tok * Dv;
  o[tid] = a0 * m; o[tid + 256] = a1 * m; o[tid + 512] = a2 * m;
}

// ---------------------------------------------------------------------------
// GEMM core: 32x64 tile, 256 threads, 2x4 acc/thread, reg-prefetch K-chunks.
// ---------------------------------------------------------------------------
template<bool BIAS, bool RELU>
__device__ __forceinline__ void gemm_core(
    const float* __restrict__ A, int lda,
    const float* __restrict__ W, int ldw,
    const float* __restrict__ bias,
    float* __restrict__ C, int ldc, int c0,
    int N, int K, int row0, int n0)
{
  __shared__ float sA[16][34];
  __shared__ float sB[16][68];

  const int tid = threadIdx.x;
  const int tm = tid >> 4;
  const int tn = tid & 15;

  float acc[2][4] = {};

  const int rowA = tid >> 2;
  const int kq = (tid & 3) << 2;
  const bool aact = tid < 128;
  const bool wval = (n0 + rowA) < N;

  const float* Ap = A + (size_t)(row0 + (rowA & 31)) * lda + kq;
  const float* Wp = W + (size_t)(wval ? (n0 + rowA) : 0) * ldw + kq;

  float4 av = float4{0, 0, 0, 0}, bv = float4{0, 0, 0, 0};
  if (aact) av = *(const float4*)Ap;
  if (wval) bv = *(const float4*)Wp;

  int k0 = 0;
  while (true) {
    __syncthreads();
    if (aact) {
      sA[kq + 0][rowA] = av.x; sA[kq + 1][rowA] = av.y;
      sA[kq + 2][rowA] = av.z; sA[kq + 3][rowA] = av.w;
    }
    sB[kq + 0][rowA] = bv.x; sB[kq + 1][rowA] = bv.y;
    sB[kq + 2][rowA] = bv.z; sB[kq + 3][rowA] = bv.w;
    __syncthreads();

    const int kn = k0 + 16;
    const bool more = kn < K;
    if (more) {
      if (aact) av = *(const float4*)(Ap + kn);
      if (wval) bv = *(const float4*)(Wp + kn);
    }

#pragma unroll
    for (int kk = 0; kk < 16; ++kk) {
      const float2 a = *(const float2*)&sA[kk][tm * 2];
      const float4 b = *(const float4*)&sB[kk][tn * 4];
      acc[0][0] += a.x * b.x; acc[0][1] += a.x * b.y;
      acc[0][2] += a.x * b.z; acc[0][3] += a.x * b.w;
      acc[1][0] += a.y * b.x; acc[1][1] += a.y * b.y;
      acc[1][2] += a.y * b.z; acc[1][3] += a.y * b.w;
    }

    if (!more) break;
    k0 = kn;
  }

#pragma unroll
  for (int i = 0; i < 2; ++i) {
    const int row = row0 + tm * 2 + i;
    float* crow = C + (size_t)row * ldc + c0;
#pragma unroll
    for (int j = 0; j < 4; ++j) {
      const int col = n0 + tn * 4 + j;
      if (col < N) {
        float v = acc[i][j];
        if (BIAS) v += bias[col];
        if (RELU) v = fmaxf(v, 0.0f);
        crow[col] = v;
      }
    }
  }
}

template<bool BIAS, bool RELU>
__global__ __launch_bounds__(256) void gemm_tn(
    const float* __restrict__ A, int lda,
    const float* __restrict__ W, int ldw,
    const float* __restrict__ bias,
    float* __restrict__ C, int ldc, int c0,
    int N, int K)
{
  gemm_core<BIAS, RELU>(A, lda, W, ldw, bias, C, ldc, c0, N, K,
                        blockIdx.x * 32, blockIdx.y * 64);
}

// ---------------------------------------------------------------------------
// heads: everything downstream of xfeat in one launch.
//  y in [0,4): head = xfeat @ aw^T + ab      (64-col slabs)
//  y == 4:    relh = xfeat @ rwc^T + rbc    (arc-head folded into rel_h)
//  y == 5:    reld = xfeat @ rw[:,256:]^T
// ---------------------------------------------------------------------------
__global__ __launch_bounds__(256) void heads(
    const float* __restrict__ xfeat, const float* __restrict__ aw,
    const float* __restrict__ ab, const float* __restrict__ rwc,
    const float* __restrict__ rbc, const float* __restrict__ rw,
    float* __restrict__ head, float* __restrict__ relh,
    float* __restrict__ reld)
{
  const int y = blockIdx.y;
  if (y < 4)
    gemm_core<true, false>(xfeat, 256, aw, 256, ab, head, 256, 0,
                           256, 256, blockIdx.x * 32, y * 64);
  else if (y == 4)
    gemm_core<true, false>(xfeat, 256, rwc, 256, rbc, relh, 50, 0,
                           50, 256, blockIdx.x * 32, 0);
  else
    gemm_core<false, false>(xfeat, 256, rw + 256, 512, nullptr, reld, 50, 0,
                            50, 256, blockIdx.x * 32, 0);
}

// ---------------------------------------------------------------------------
// Fused scores: blocks [0,512) arc 32x32 tiles; [512,4608) rel broadcast-add.
// ---------------------------------------------------------------------------
__global__ __launch_bounds__(256) void fused_scores(
    const float* __restrict__ head, const float* __restrict__ dep,
    const float* __restrict__ relh, const float* __restrict__ reld,
    float* __restrict__ arc_out, float* __restrict__ rel_out)
{
  __shared__ float smem[6450];
  const int tid = threadIdx.x;

  if (blockIdx.x < 512) {
    const int blk = blockIdx.x;
    const int b = blk >> 4;
    const int tile = blk & 15;
    const int i0 = (tile >> 2) * 32;
    const int j0 = (tile & 3) * 32;

    float (*sh)[33] = (float(*)[33])smem;
    float (*sd)[33] = (float(*)[33])(smem + 1056);

    const int r = tid >> 3;
    const int c = (tid & 7) << 2;
    const int ty = tid >> 4;
    const int tx = tid & 15;

    float acc00 = 0.f, acc01 = 0.f, acc10 = 0.f, acc11 = 0.f;
    const float* hb = head + (size_t)(b * Sv + i0) * Hv;
    const float* db = dep + (size_t)(b * Sv + j0) * Hv;

    for (int k0 = 0; k0 < Hv; k0 += 32) {
      float4 hv = *(const float4*)(hb + (size_t)r * Hv + k0 + c);
      float4 dv = *(const float4*)(db + (size_t)r * Hv + k0 + c);
      __syncthreads();
      sh[r][c] = hv.x; sh[r][c+1] = hv.y; sh[r][c+2] = hv.z; sh[r][c+3] = hv.w;
      sd[r][c] = dv.x; sd[r][c+1] = dv.y; sd[r][c+2] = dv.z; sd[r][c+3] = dv.w;
      __syncthreads();
#pragma unroll
      for (int kk = 0; kk < 32; ++kk) {
        float h0 = sh[ty][kk],  h1 = sh[ty + 16][kk];
        float d0 = sd[tx][kk],  d1 = sd[tx + 16][kk];
        acc00 += h0 * d0; acc01 += h0 * d1;
        acc10 += h1 * d0; acc11 += h1 * d1;
      }
    }

    float* ob = arc_out + (size_t)b * Sv * Sv;
    ob[(i0 + ty) * Sv + j0 + tx]           = acc00;
    ob[(i0 + ty) * Sv + j0 + tx + 16]      = acc01;
    ob[(i0 + ty + 16) * Sv + j0 + tx]      = acc10;
    ob[(i0 + ty + 16) * Sv + j0 + tx + 16] = acc11;
  } else {
    const int bi = blockIdx.x - 512;
    const int b = bi >> 7;

    float* srd = smem;
    float* shi = smem + 6400;

    const float4* rd4 = (const float4*)(reld + (size_t)b * Sv * Rv);
    float4* s4 = (float4*)srd;
    for (int n = tid; n < (Sv * Rv / 4); n += 256) s4[n] = rd4[n];
    if (tid < Rv) shi[tid] = relh[(size_t)bi * Rv + tid];
    __syncthreads();

    float2* out2 = (float2*)(rel_out + (size_t)bi * Sv * Rv);
    for (int n = tid; n < (Sv * Rv / 2); n += 256) {
      const int j = n / 25;
      const int r = (n - j * 25) * 2;
      const float* rdj = srd + j * Rv;
      float2 v;
      v.x = shi[r]     + rdj[r];
      v.y = shi[r + 1] + rdj[r + 1];
      out2[n] = v;
    }
  }
}

// ---------------------------------------------------------------------------
extern "C" void kernel_launch(void* const* d_in, const int* in_sizes, int n_in,
                              void* d_out, int out_size, void* d_ws, size_t ws_size,
                              hipStream_t stream) {
  const int*   words   = (const int*)d_in[0];
  const int*   pos_ids = (const int*)d_in[1];
  const float* audio   = (const float*)d_in[2];
  const float* st      = (const float*)d_in[3];
  const float* et      = (const float*)d_in[4];
  const float* word_W  = (const float*)d_in[5];
  const float* pos_W   = (const float*)d_in[6];
  const float* audio_w = (const float*)d_in[7];
  const float* audio_b = (const float*)d_in[8];
  const float* m1w     = (const float*)d_in[9];
  const float* m1b     = (const float*)d_in[10];
  const float* m2w     = (const float*)d_in[11];
  const float* m2b     = (const float*)d_in[12];
  const float* aw      = (const float*)d_in[13];
  const float* ab      = (const float*)d_in[14];
  const float* rw      = (const float*)d_in[15];
  const float* rb      = (const float*)d_in[16];

  float* out = (float*)d_out;
  float* ws = (float*)d_ws;

  const size_t NT = (size_t)Bv * Sv;            // 4096 tokens

  // chunkSum (32*250*768 = 6.14M floats = 24.6 MB) lives in d_out's rel
  // region as scratch: it is dead after seg_sum, long before fused_scores
  // overwrites the rel region. Deterministic across graph replays (fully
  // rewritten by stage1 each call before any read).
  float* rel_out  = out + (size_t)Bv * Sv * Sv;
  float* chunkSum = rel_out;

  // ws layout (~31.2 MB, same proven footprint as earlier rounds)
  float* smean = ws;                            // NT*768
  float* x0    = smean + NT * Dv;               // NT*256
  float* h1    = x0    + NT * 256;              // NT*256
  float* xfeat = h1    + NT * 256;              // NT*256 (dep)
  float* head  = xfeat + NT * 256;              // NT*256
  float* relh  = head  + NT * 256;              // NT*50
  float* reld  = relh  + NT * Rv;               // NT*50
  float* wpad  = reld  + NT * Rv;               // 256*256
  float* rwc   = wpad  + 256 * 256;             // 50*256
  float* rbc   = rwc   + Rv * 256;              // 50

  stage1<<<Bv * NCH + 256 + 512 + Rv + 1, 256, 0, stream>>>(
      audio, words, pos_ids, word_W, pos_W, m1w, rw, aw, ab, rb,
      chunkSum, wpad, x0, rwc, rbc);

  seg_sum<<<(int)NT, 256, 0, stream>>>(audio, chunkSum, st, et, smean);

  // audio projection: x0[:, 150:250] = smean @ audio_w.T + audio_b
  gemm_tn<true, false><<<dim3(128, 2), 256, 0, stream>>>(
      smean, Dv, audio_w, Dv, audio_b, x0, 256, 150, 100, Dv);

  // mlp1: h1 = relu(x0 @ wpad.T + m1b)
  gemm_tn<true, true><<<dim3(128, 4), 256, 0, stream>>>(
      x0, 256, wpad, 256, m1b, h1, 256, 0, 256, 256);

  // mlp2: xfeat = relu(h1 @ m2w.T + m2b)
  gemm_tn<true, true><<<dim3(128, 4), 256, 0, stream>>>(
      h1, 256, m2w, 256, m2b, xfeat, 256, 0, 256, 256);

  // head / relh / reld in one launch
  heads<<<dim3(128, 6), 256, 0, stream>>>(
      xfeat, aw, ab, rwc, rbc, rw, head, relh, reld);

  fused_scores<<<512 + (int)NT, 256, 0, stream>>>(
      head, xfeat, relh, reld, out, rel_out);
}